// Round 8
// baseline (457.323 us; speedup 1.0000x reference)
//
#include <hip/hip_runtime.h>
#include <hip/hip_cooperative_groups.h>

// Convex upsample, round 8: SINGLE cooperative kernel.
//   Phase A (grid-stride): w1/w2 -> bf16 frag layouts; NHWC pad ring zero;
//                          feat NCHW f32 -> padded NHWC bf16 (dual 256-thr
//                          transpose tasks per 512-thr block).
//   grid.sync()            (device-scope fence; cross-XCD L2 handled)
//   Phase B (grid-stride): proven R5/R7 tile body: feat tile via
//                          global_load_lds dwordx4 (XOR swizzle), GEMM1 conv3x3
//                          -> relu -> sH overlay -> GEMM2 1x1 (n-tile==tap) ->
//                          register softmax -> convex combine -> coalesced store.
// Fallbacks: 3-kernel R7 path if cooperative occupancy < 1; fb kernel if ws tiny.

namespace cg = cooperative_groups;

using frag_ab = __attribute__((ext_vector_type(8))) short;   // 8 bf16
using frag_cd = __attribute__((ext_vector_type(4))) float;   // 4 f32
typedef __attribute__((ext_vector_type(8))) unsigned short ushort8;

static __device__ __forceinline__ unsigned short f2bf(float f) {
    unsigned u = __builtin_bit_cast(unsigned, f);
    u += 0x7fff + ((u >> 16) & 1);          // RNE
    return (unsigned short)(u >> 16);
}
static __device__ __forceinline__ unsigned int pkbf(float lo, float hi) {
    return (unsigned int)f2bf(lo) | ((unsigned int)f2bf(hi) << 16);
}

// ================= cooperative mega-kernel =================
__global__ __launch_bounds__(512, 4) void convex_up_coop(
    const float* __restrict__ depth, const float* __restrict__ feat,
    const float* __restrict__ w1, const float* __restrict__ w2,
    unsigned short* __restrict__ nhwc, unsigned short* __restrict__ w1bf,
    unsigned short* __restrict__ w2bf, float* __restrict__ out)
{
    constexpr int H = 128, W = 416, OW = 1664;
    constexpr int RS = 418 * 64;                 // padded NHWC row stride (ushorts)

    __shared__ __align__(16) unsigned char smem[42768];

    const int tid  = threadIdx.x;
    const int bid  = blockIdx.x;
    const int G    = gridDim.x;                  // 256 or 512

    // ---------- Phase A.1: weight fragment layouts ----------
    for (int i = bid * 512 + tid; i < 36864; i += G * 512) {
        int j = i & 7, oc = (i >> 3) & 63, g = i >> 9;
        int q = g & 3, kh = (g >> 2) & 1, tap = g >> 3;
        int ic = kh * 32 + q * 8 + j;
        w1bf[i] = f2bf(w1[(oc * 64 + ic) * 9 + (tap / 3) * 3 + (tap % 3)]);
    }
    for (int i = bid * 512 + tid; i < 9216; i += G * 512) {
        int j = i & 7, ch = (i >> 3) % 144, g = (i >> 3) / 144;
        int q = g & 3, kh = g >> 2;
        w2bf[i] = f2bf(w2[ch * 64 + (kh * 32 + q * 8 + j)]);
    }
    // ---------- Phase A.2: NHWC pad ring ----------
    for (int i = bid * 512 + tid; i < 69888; i += G * 512) {
        int b = i / 8736, rem = i - b * 8736;
        int pos = rem >> 3, pack = rem & 7;
        int row, w;
        if (pos < 836) { row = (pos < 418) ? 0 : 129; w = (pos < 418) ? pos : pos - 418; }
        else           { int t = pos - 836; row = 1 + (t >> 1); w = (t & 1) ? 417 : 0; }
        ushort8 z = {0, 0, 0, 0, 0, 0, 0, 0};
        *(ushort8*)&nhwc[(((size_t)b * 130 + row) * 418 + w) * 64 + pack * 8] = z;
    }

    // ---------- Phase A.3: transpose, dual 256-thr tasks ----------
    // 13312 tasks = (b*128+h)*13 + wt ; per iter a block does tasks 2*bid, 2*bid+1.
    {
        const int half = tid >> 8, stid = tid & 255;
        float* sT = (float*)smem + half * 2112;          // 64*33 floats each
        const int iterA = 13312 / (2 * G);               // exact for G in {256,512}
        for (int it = 0; it < iterA; ++it) {
            const int t2 = it * 2 * G + 2 * bid + half;
            const int b = t2 / 1664, rem = t2 - b * 1664;
            const int h = rem / 13, w0 = (rem - h * 13) * 32;
            __syncthreads();
            const int seg = stid & 7, crd = stid >> 3;
            #pragma unroll
            for (int pass = 0; pass < 2; ++pass) {
                const int c = crd + 32 * pass;
                float4 v = *(const float4*)&feat[(((size_t)b * 64 + c) * 128 + h) * 416 + w0 + seg * 4];
                *(float4*)&sT[c * 33 + seg * 4] = v;
            }
            __syncthreads();
            const int w = stid >> 3, j = stid & 7;
            float f[8];
            #pragma unroll
            for (int k = 0; k < 8; ++k) f[k] = sT[(j * 8 + k) * 33 + w];
            uint4 o;
            o.x = pkbf(f[0], f[1]); o.y = pkbf(f[2], f[3]);
            o.z = pkbf(f[4], f[5]); o.w = pkbf(f[6], f[7]);
            *(uint4*)&nhwc[(((size_t)b * 130 + h + 1) * 418 + (w0 + w + 1)) * 64 + j * 8] = o;
        }
    }

    __threadfence();
    cg::this_grid().sync();

    // ---------- Phase B: main tiles, grid-stride over 1664 ----------
    unsigned short* sF = (unsigned short*)smem;          // 41472 B
    float* sD = (float*)(smem + 41472);                  // 324 floats

    const int wv   = tid >> 6;
    const int lane = tid & 63;
    const int q    = lane >> 4;
    const int ln   = lane & 15;

    for (int t = bid; t < 1664; t += G) {
        const int bw = t % 26, bh = (t / 26) % 8, b = t / 208;
        const int h0 = bh * 16, w0 = bw * 16;

        __syncthreads();   // prior iteration fully done with sF/sD

        // depth tile (18x18 halo, zero-pad)
        if (tid < 324) {
            int lr = tid / 18, lc = tid % 18;
            int gh = h0 - 1 + lr, gw = w0 - 1 + lc;
            float v = 0.f;
            if ((unsigned)gh < (unsigned)H && (unsigned)gw < (unsigned)W)
                v = depth[((size_t)b * H + gh) * W + gw];
            sD[tid] = v;
        }

        // feat tile: 2592 16B-chunks via global_load_lds
        const unsigned short* gbase = nhwc + ((size_t)(b * 130 + h0) * 418 + w0) * 64;
        #pragma unroll
        for (int k = 0; k < 6; ++k) {
            int i = wv + 8 * k;
            int c = i * 64 + lane;
            if (c < 2592) {
                int r = c / 144, m = c - r * 144;
                int col = m >> 3, iccs = m & 7;
                int icc = iccs ^ (col & 7);       // XOR swizzle (source side)
                const unsigned short* g = gbase + (size_t)r * RS + col * 64 + icc * 8;
                __builtin_amdgcn_global_load_lds((const __attribute__((address_space(1))) void*)g,
                                                 (__attribute__((address_space(3))) void*)&sF[c * 8],
                                                 16, 0, 0);
            }
        }
        __syncthreads();

        // GEMM1: conv3x3
        frag_cd acc1[2][4];
        #pragma unroll
        for (int mt = 0; mt < 2; ++mt)
            #pragma unroll
            for (int nt = 0; nt < 4; ++nt) acc1[mt][nt] = frag_cd{0.f, 0.f, 0.f, 0.f};

        #pragma unroll
        for (int tap = 0; tap < 9; ++tap) {
            const int ky = tap / 3, kx = tap % 3;
            #pragma unroll
            for (int kh = 0; kh < 2; ++kh) {
                frag_ab a[2];
                #pragma unroll
                for (int mt = 0; mt < 2; ++mt) {
                    int r = 2 * wv + mt + ky, col = ln + kx;
                    int slot = (r * 18 + col) * 8 + ((kh * 4 + q) ^ (col & 7));
                    a[mt] = *(const frag_ab*)&sF[slot * 8];
                }
                frag_ab bf[4];
                #pragma unroll
                for (int nt = 0; nt < 4; ++nt)
                    bf[nt] = *(const frag_ab*)&w1bf[(size_t)((tap * 2 + kh) * 4 + q) * 512 + (nt * 16 + ln) * 8];
                #pragma unroll
                for (int mt = 0; mt < 2; ++mt)
                    #pragma unroll
                    for (int nt = 0; nt < 4; ++nt)
                        acc1[mt][nt] = __builtin_amdgcn_mfma_f32_16x16x32_bf16(a[mt], bf[nt], acc1[mt][nt], 0, 0, 0);
            }
        }

        __syncthreads();   // all waves done reading sF; overlay per-wave sH

        unsigned short* sH = sF + wv * 2304;   // [px32][72] bf16
        #pragma unroll
        for (int mt = 0; mt < 2; ++mt)
            #pragma unroll
            for (int nt = 0; nt < 4; ++nt)
                #pragma unroll
                for (int r = 0; r < 4; ++r)
                    sH[(mt * 16 + q * 4 + r) * 72 + nt * 16 + ln] = f2bf(fmaxf(acc1[mt][nt][r], 0.f));
        // same-wave LDS RAW: compiler-inserted lgkmcnt, no barrier needed

        // GEMM2: logits, n-tile == tap
        frag_cd acc2[2][9];
        #pragma unroll
        for (int mt = 0; mt < 2; ++mt)
            #pragma unroll
            for (int nt = 0; nt < 9; ++nt) acc2[mt][nt] = frag_cd{0.f, 0.f, 0.f, 0.f};

        #pragma unroll
        for (int kh = 0; kh < 2; ++kh) {
            frag_ab a2[2];
            #pragma unroll
            for (int mt = 0; mt < 2; ++mt)
                a2[mt] = *(const frag_ab*)&sH[(mt * 16 + ln) * 72 + kh * 32 + q * 8];
            #pragma unroll
            for (int nt = 0; nt < 9; ++nt) {
                frag_ab b2 = *(const frag_ab*)&w2bf[(size_t)((kh * 4 + q) * 144 + nt * 16 + ln) * 8];
                acc2[0][nt] = __builtin_amdgcn_mfma_f32_16x16x32_bf16(a2[0], b2, acc2[0][nt], 0, 0, 0);
                acc2[1][nt] = __builtin_amdgcn_mfma_f32_16x16x32_bf16(a2[1], b2, acc2[1][nt], 0, 0, 0);
            }
        }

        // softmax over 9 taps + convex combine; stage into own slice
        float* sOutw = (float*)sH;
        #pragma unroll
        for (int mt = 0; mt < 2; ++mt) {
            const int prow = 2 * wv + mt;
            #pragma unroll
            for (int r = 0; r < 4; ++r) {
                const int pcol = q * 4 + r;
                float lg[9];
                #pragma unroll
                for (int tt = 0; tt < 9; ++tt) lg[tt] = acc2[mt][tt][r];
                float mx = lg[0];
                #pragma unroll
                for (int tt = 1; tt < 9; ++tt) mx = fmaxf(mx, lg[tt]);
                float sum = 0.f, up = 0.f;
                #pragma unroll
                for (int tt = 0; tt < 9; ++tt) {
                    float e = __expf(lg[tt] - mx);
                    sum += e;
                    up  += e * sD[(prow + tt / 3) * 18 + (pcol + tt % 3)];
                }
                sOutw[(mt * 16 + pcol) * 17 + ln] = up / sum;
            }
        }
        float* outb = out + (size_t)b * 512 * OW + (size_t)(h0 + 2 * wv) * 4 * OW + w0 * 4;
        const int row_o = lane >> 3;
        const int mt_o  = row_o >> 2, sy_o = row_o & 3;
        #pragma unroll
        for (int v = 0; v < 2; ++v) {
            float4 o;
            #pragma unroll
            for (int e = 0; e < 4; ++e) {
                int j = (lane & 7) * 8 + v * 4 + e;
                o[e] = sOutw[(mt_o * 16 + (j >> 2)) * 17 + sy_o * 4 + (j & 3)];
            }
            *(float4*)&outb[(size_t)row_o * OW + (lane & 7) * 8 + v * 4] = o;
        }
    }
}

// ================= fallback kernels (R7 path) =================
__global__ void prep(const float* __restrict__ w1, const float* __restrict__ w2,
                     unsigned short* __restrict__ w1bf, unsigned short* __restrict__ w2bf,
                     unsigned short* __restrict__ nhwc, int do_pad) {
    int i = blockIdx.x * 256 + threadIdx.x;
    if (i < 36864) {
        int j = i & 7, oc = (i >> 3) & 63, g = i >> 9;
        int q = g & 3, kh = (g >> 2) & 1, tap = g >> 3;
        int ic = kh * 32 + q * 8 + j;
        w1bf[i] = f2bf(w1[(oc * 64 + ic) * 9 + (tap / 3) * 3 + (tap % 3)]);
    }
    if (i < 9216) {
        int j = i & 7, ch = (i >> 3) % 144, g = (i >> 3) / 144;
        int q = g & 3, kh = g >> 2;
        w2bf[i] = f2bf(w2[ch * 64 + (kh * 32 + q * 8 + j)]);
    }
    if (do_pad && i < 69888) {
        int b = i / 8736, rem = i - b * 8736;
        int pos = rem >> 3, pack = rem & 7;
        int row, w;
        if (pos < 836) { row = (pos < 418) ? 0 : 129; w = (pos < 418) ? pos : pos - 418; }
        else           { int t = pos - 836; row = 1 + (t >> 1); w = (t & 1) ? 417 : 0; }
        ushort8 z = {0, 0, 0, 0, 0, 0, 0, 0};
        *(ushort8*)&nhwc[(((size_t)b * 130 + row) * 418 + w) * 64 + pack * 8] = z;
    }
}

__global__ __launch_bounds__(256, 8) void nchw_to_nhwc3(const float* __restrict__ feat,
                                                        unsigned short* __restrict__ nhwc) {
    __shared__ float sT[64 * 33];
    const int b = blockIdx.z, h = blockIdx.y, w0 = blockIdx.x * 32;
    const int tid = threadIdx.x;
    const int seg = tid & 7, crd = tid >> 3;
    #pragma unroll
    for (int pass = 0; pass < 2; ++pass) {
        const int c = crd + 32 * pass;
        float4 v = *(const float4*)&feat[(((size_t)b * 64 + c) * 128 + h) * 416 + w0 + seg * 4];
        *(float4*)&sT[c * 33 + seg * 4] = v;
    }
    __syncthreads();
    const int w = tid >> 3, j = tid & 7;
    float f[8];
    #pragma unroll
    for (int k = 0; k < 8; ++k) f[k] = sT[(j * 8 + k) * 33 + w];
    uint4 o;
    o.x = pkbf(f[0], f[1]); o.y = pkbf(f[2], f[3]);
    o.z = pkbf(f[4], f[5]); o.w = pkbf(f[6], f[7]);
    *(uint4*)&nhwc[(((size_t)b * 130 + h + 1) * 418 + (w0 + w + 1)) * 64 + j * 8] = o;
}

__global__ __launch_bounds__(512, 4) void convex_up_mfma3(
    const float* __restrict__ depth, const unsigned short* __restrict__ nhwc,
    const unsigned short* __restrict__ w1bf, const unsigned short* __restrict__ w2bf,
    float* __restrict__ out)
{
    constexpr int H = 128, W = 416, OW = 1664;
    constexpr int RS = 418 * 64;
    __shared__ __align__(16) unsigned short sF[2592 * 8];
    __shared__ float sD[18 * 18];
    const int tid = threadIdx.x, wv = tid >> 6, lane = tid & 63;
    const int q = lane >> 4, ln = lane & 15;
    const int bw = blockIdx.x, bh = blockIdx.y, b = blockIdx.z;
    const int h0 = bh * 16, w0 = bw * 16;
    if (tid < 324) {
        int lr = tid / 18, lc = tid % 18;
        int gh = h0 - 1 + lr, gw = w0 - 1 + lc;
        float v = 0.f;
        if ((unsigned)gh < (unsigned)H && (unsigned)gw < (unsigned)W)
            v = depth[((size_t)b * H + gh) * W + gw];
        sD[tid] = v;
    }
    const unsigned short* gbase = nhwc + ((size_t)(b * 130 + h0) * 418 + w0) * 64;
    #pragma unroll
    for (int k = 0; k < 6; ++k) {
        int i = wv + 8 * k;
        int c = i * 64 + lane;
        if (c < 2592) {
            int r = c / 144, m = c - r * 144;
            int col = m >> 3, iccs = m & 7;
            int icc = iccs ^ (col & 7);
            const unsigned short* g = gbase + (size_t)r * RS + col * 64 + icc * 8;
            __builtin_amdgcn_global_load_lds((const __attribute__((address_space(1))) void*)g,
                                             (__attribute__((address_space(3))) void*)&sF[c * 8],
                                             16, 0, 0);
        }
    }
    __syncthreads();
    frag_cd acc1[2][4];
    for (int mt = 0; mt < 2; ++mt) for (int nt = 0; nt < 4; ++nt) acc1[mt][nt] = frag_cd{0.f,0.f,0.f,0.f};
    #pragma unroll
    for (int tap = 0; tap < 9; ++tap) {
        const int ky = tap / 3, kx = tap % 3;
        #pragma unroll
        for (int kh = 0; kh < 2; ++kh) {
            frag_ab a[2];
            #pragma unroll
            for (int mt = 0; mt < 2; ++mt) {
                int r = 2 * wv + mt + ky, col = ln + kx;
                int slot = (r * 18 + col) * 8 + ((kh * 4 + q) ^ (col & 7));
                a[mt] = *(const frag_ab*)&sF[slot * 8];
            }
            frag_ab bf[4];
            #pragma unroll
            for (int nt = 0; nt < 4; ++nt)
                bf[nt] = *(const frag_ab*)&w1bf[(size_t)((tap * 2 + kh) * 4 + q) * 512 + (nt * 16 + ln) * 8];
            #pragma unroll
            for (int mt = 0; mt < 2; ++mt)
                #pragma unroll
                for (int nt = 0; nt < 4; ++nt)
                    acc1[mt][nt] = __builtin_amdgcn_mfma_f32_16x16x32_bf16(a[mt], bf[nt], acc1[mt][nt], 0, 0, 0);
        }
    }
    __syncthreads();
    unsigned short* sH = sF + wv * 2304;
    #pragma unroll
    for (int mt = 0; mt < 2; ++mt)
        #pragma unroll
        for (int nt = 0; nt < 4; ++nt)
            #pragma unroll
            for (int r = 0; r < 4; ++r)
                sH[(mt * 16 + q * 4 + r) * 72 + nt * 16 + ln] = f2bf(fmaxf(acc1[mt][nt][r], 0.f));
    frag_cd acc2[2][9];
    for (int mt = 0; mt < 2; ++mt) for (int nt = 0; nt < 9; ++nt) acc2[mt][nt] = frag_cd{0.f,0.f,0.f,0.f};
    #pragma unroll
    for (int kh = 0; kh < 2; ++kh) {
        frag_ab a2[2];
        #pragma unroll
        for (int mt = 0; mt < 2; ++mt)
            a2[mt] = *(const frag_ab*)&sH[(mt * 16 + ln) * 72 + kh * 32 + q * 8];
        #pragma unroll
        for (int nt = 0; nt < 9; ++nt) {
            frag_ab b2 = *(const frag_ab*)&w2bf[(size_t)((kh * 4 + q) * 144 + nt * 16 + ln) * 8];
            acc2[0][nt] = __builtin_amdgcn_mfma_f32_16x16x32_bf16(a2[0], b2, acc2[0][nt], 0, 0, 0);
            acc2[1][nt] = __builtin_amdgcn_mfma_f32_16x16x32_bf16(a2[1], b2, acc2[1][nt], 0, 0, 0);
        }
    }
    float* sOutw = (float*)sH;
    #pragma unroll
    for (int mt = 0; mt < 2; ++mt) {
        const int prow = 2 * wv + mt;
        #pragma unroll
        for (int r = 0; r < 4; ++r) {
            const int pcol = q * 4 + r;
            float lg[9];
            #pragma unroll
            for (int t = 0; t < 9; ++t) lg[t] = acc2[mt][t][r];
            float mx = lg[0];
            #pragma unroll
            for (int t = 1; t < 9; ++t) mx = fmaxf(mx, lg[t]);
            float sum = 0.f, up = 0.f;
            #pragma unroll
            for (int t = 0; t < 9; ++t) {
                float e = __expf(lg[t] - mx);
                sum += e; up += e * sD[(prow + t / 3) * 18 + (pcol + t % 3)];
            }
            sOutw[(mt * 16 + pcol) * 17 + ln] = up / sum;
        }
    }
    float* outb = out + (size_t)b * 512 * OW + (size_t)(h0 + 2 * wv) * 4 * OW + w0 * 4;
    const int row_o = lane >> 3, mt_o = row_o >> 2, sy_o = row_o & 3;
    #pragma unroll
    for (int v = 0; v < 2; ++v) {
        float4 o;
        #pragma unroll
        for (int e = 0; e < 4; ++e) {
            int j = (lane & 7) * 8 + v * 4 + e;
            o[e] = sOutw[(mt_o * 16 + (j >> 2)) * 17 + sy_o * 4 + (j & 3)];
        }
        *(float4*)&outb[(size_t)row_o * OW + (lane & 7) * 8 + v * 4] = o;
    }
}

__global__ __launch_bounds__(256, 3) void convex_up_mfma_fb(
    const float* __restrict__ depth, const float* __restrict__ feat,
    const unsigned short* __restrict__ w1bf, const unsigned short* __restrict__ w2bf,
    float* __restrict__ out)
{
    constexpr int H = 128, W = 416, OW = 1664;
    __shared__ unsigned short sF[8 * 10 * 18 * 8];
    __shared__ unsigned short sH[4][32 * 72];
    __shared__ float sD[10 * 18];
    const int tid = threadIdx.x, wv = tid >> 6, lane = tid & 63;
    const int q = lane >> 4, ln = lane & 15;
    const int bw = blockIdx.x, bh = blockIdx.y, b = blockIdx.z;
    const int h0 = bh * 8, w0 = bw * 16;
    if (tid < 180) {
        int lr = tid / 18, lc = tid % 18;
        int gh = h0 - 1 + lr, gw = w0 - 1 + lc;
        float v = 0.f;
        if ((unsigned)gh < (unsigned)H && (unsigned)gw < (unsigned)W)
            v = depth[((size_t)b * H + gh) * W + gw];
        sD[tid] = v;
    }
    for (int idx = tid; idx < 11520; idx += 256) {
        int ic = idx / 180, rem = idx - ic * 180;
        int lr = rem / 18, lc = rem - lr * 18;
        int gh = h0 - 1 + lr, gw = w0 - 1 + lc;
        float v = 0.f;
        if ((unsigned)gh < (unsigned)H && (unsigned)gw < (unsigned)W)
            v = feat[(((size_t)b * 64 + ic) * H + gh) * W + gw];
        sF[(((ic >> 3) * 10 + lr) * 18 + lc) * 8 + (ic & 7)] = f2bf(v);
    }
    __syncthreads();
    frag_cd acc1[2][4];
    for (int mt = 0; mt < 2; ++mt) for (int nt = 0; nt < 4; ++nt) acc1[mt][nt] = frag_cd{0.f,0.f,0.f,0.f};
    #pragma unroll
    for (int tap = 0; tap < 9; ++tap) {
        const int ky = tap / 3, kx = tap % 3;
        #pragma unroll
        for (int kh = 0; kh < 2; ++kh) {
            frag_ab a[2];
            #pragma unroll
            for (int mt = 0; mt < 2; ++mt)
                a[mt] = *(const frag_ab*)&sF[(((kh * 4 + q) * 10 + 2 * wv + mt + ky) * 18 + ln + kx) * 8];
            frag_ab bf[4];
            #pragma unroll
            for (int nt = 0; nt < 4; ++nt)
                bf[nt] = *(const frag_ab*)&w1bf[(size_t)((tap * 2 + kh) * 4 + q) * 512 + (nt * 16 + ln) * 8];
            #pragma unroll
            for (int mt = 0; mt < 2; ++mt)
                #pragma unroll
                for (int nt = 0; nt < 4; ++nt)
                    acc1[mt][nt] = __builtin_amdgcn_mfma_f32_16x16x32_bf16(a[mt], bf[nt], acc1[mt][nt], 0, 0, 0);
        }
    }
    #pragma unroll
    for (int mt = 0; mt < 2; ++mt)
        #pragma unroll
        for (int nt = 0; nt < 4; ++nt)
            #pragma unroll
            for (int r = 0; r < 4; ++r)
                sH[wv][(mt * 16 + q * 4 + r) * 72 + nt * 16 + ln] = f2bf(fmaxf(acc1[mt][nt][r], 0.f));
    frag_cd acc2[2][9];
    for (int mt = 0; mt < 2; ++mt) for (int nt = 0; nt < 9; ++nt) acc2[mt][nt] = frag_cd{0.f,0.f,0.f,0.f};
    #pragma unroll
    for (int kh = 0; kh < 2; ++kh) {
        frag_ab a2[2];
        #pragma unroll
        for (int mt = 0; mt < 2; ++mt)
            a2[mt] = *(const frag_ab*)&sH[wv][(mt * 16 + ln) * 72 + kh * 32 + q * 8];
        #pragma unroll
        for (int nt = 0; nt < 9; ++nt) {
            frag_ab b2 = *(const frag_ab*)&w2bf[(size_t)((kh * 4 + q) * 144 + nt * 16 + ln) * 8];
            acc2[0][nt] = __builtin_amdgcn_mfma_f32_16x16x32_bf16(a2[0], b2, acc2[0][nt], 0, 0, 0);
            acc2[1][nt] = __builtin_amdgcn_mfma_f32_16x16x32_bf16(a2[1], b2, acc2[1][nt], 0, 0, 0);
        }
    }
    float* sOutw = (float*)&sH[wv][0];
    #pragma unroll
    for (int mt = 0; mt < 2; ++mt) {
        const int prow = 2 * wv + mt;
        #pragma unroll
        for (int r = 0; r < 4; ++r) {
            const int pcol = q * 4 + r;
            float lg[9];
            #pragma unroll
            for (int t = 0; t < 9; ++t) lg[t] = acc2[mt][t][r];
            float mx = lg[0];
            #pragma unroll
            for (int t = 1; t < 9; ++t) mx = fmaxf(mx, lg[t]);
            float sum = 0.f, up = 0.f;
            #pragma unroll
            for (int t = 0; t < 9; ++t) {
                float e = __expf(lg[t] - mx);
                sum += e; up += e * sD[(prow + t / 3) * 18 + (pcol + t % 3)];
            }
            sOutw[(mt * 16 + pcol) * 17 + ln] = up / sum;
        }
    }
    float* outb = out + (size_t)b * 512 * OW + (size_t)(h0 + 2 * wv) * 4 * OW + w0 * 4;
    const int row_o = lane >> 3, mt_o = row_o >> 2, sy_o = row_o & 3;
    #pragma unroll
    for (int v = 0; v < 2; ++v) {
        float4 o;
        #pragma unroll
        for (int e = 0; e < 4; ++e) {
            int j = (lane & 7) * 8 + v * 4 + e;
            o[e] = sOutw[(mt_o * 16 + (j >> 2)) * 17 + sy_o * 4 + (j & 3)];
        }
        *(float4*)&outb[(size_t)row_o * OW + (lane & 7) * 8 + v * 4] = o;
    }
}

extern "C" void kernel_launch(void* const* d_in, const int* in_sizes, int n_in,
                              void* d_out, int out_size, void* d_ws, size_t ws_size,
                              hipStream_t stream) {
    const float* depth = (const float*)d_in[0];
    const float* feat  = (const float*)d_in[1];
    const float* w1    = (const float*)d_in[2];
    const float* w2    = (const float*)d_in[3];
    float* out = (float*)d_out;

    const size_t NHWC_USHORTS = (size_t)8 * 130 * 418 * 64;        // 27,827,200
    const size_t NEED = NHWC_USHORTS * 2 + (36864 + 9216) * 2;     // ~55.75 MB

    if (ws_size >= NEED) {
        unsigned short* nhwc = (unsigned short*)d_ws;
        unsigned short* w1bf = nhwc + NHWC_USHORTS;
        unsigned short* w2bf = w1bf + 36864;

        int maxB = 0;
        hipOccupancyMaxActiveBlocksPerMultiprocessor(&maxB, convex_up_coop, 512, 0);
        if (maxB >= 1) {
            int G = (maxB >= 2) ? 512 : 256;
            void* args[] = { (void*)&depth, (void*)&feat, (void*)&w1, (void*)&w2,
                             (void*)&nhwc, (void*)&w1bf, (void*)&w2bf, (void*)&out };
            hipLaunchCooperativeKernel((const void*)convex_up_coop, dim3(G), dim3(512),
                                       args, 0, stream);
        } else {
            prep<<<273, 256, 0, stream>>>(w1, w2, w1bf, w2bf, nhwc, 1);
            nchw_to_nhwc3<<<dim3(13, 128, 8), 256, 0, stream>>>(feat, nhwc);
            convex_up_mfma3<<<dim3(26, 8, 8), dim3(512), 0, stream>>>(depth, nhwc, w1bf, w2bf, out);
        }
    } else {
        unsigned short* w1bf = (unsigned short*)d_ws;
        unsigned short* w2bf = w1bf + 36864;
        prep<<<273, 256, 0, stream>>>(w1, w2, w1bf, w2bf, nullptr, 0);
        convex_up_mfma_fb<<<dim3(26, 16, 8), 256, 0, stream>>>(depth, feat, w1bf, w2bf, out);
    }
}